// Round 4
// baseline (1464.529 us; speedup 1.0000x reference)
//
#include <hip/hip_runtime.h>
#include <hip/hip_bf16.h>
#include <math.h>

typedef unsigned short u16;
typedef __attribute__((ext_vector_type(8))) short short8;     // 8 bf16 (4 VGPRs)
typedef __attribute__((ext_vector_type(4))) float f32x4;
typedef __attribute__((ext_vector_type(4))) unsigned short ushort4v;
typedef __attribute__((ext_vector_type(8))) unsigned short ushort8v;

#define DEV static __device__ __forceinline__

DEV u16 f2bf(float f) {
    unsigned int x = __builtin_bit_cast(unsigned int, f);
    x += 0x7fffu + ((x >> 16) & 1u);      // round-to-nearest-even
    return (u16)(x >> 16);
}
DEV float bf2f(u16 u) {
    unsigned int x = ((unsigned int)u) << 16;
    return __builtin_bit_cast(float, x);
}
// pack two f32 -> two bf16 (truncating) in one v_perm_b32
DEV unsigned int pk_bf_trunc(float lo, float hi) {
    return __builtin_amdgcn_perm(__builtin_bit_cast(unsigned int, hi),
                                 __builtin_bit_cast(unsigned int, lo), 0x07060302u);
}

// async global->LDS, 16B per lane; LDS dest = wave-uniform base + lane*16
DEV void gl_lds16(const u16* g, u16* l) {
    __builtin_amdgcn_global_load_lds(
        (const __attribute__((address_space(1))) void*)g,
        (__attribute__((address_space(3))) void*)l, 16, 0, 0);
}

// ---------------------------------------------------------------------------
// x fp32 -> bf16, 1 unit = 8 elems. grid = n/(256*8)
// ---------------------------------------------------------------------------
__global__ __launch_bounds__(256) void k_x2bf(
    const float* __restrict__ in, u16* __restrict__ out)
{
    int idx = blockIdx.x * 256 + threadIdx.x;
    const float4* p = (const float4*)in + (size_t)idx * 2;
    float4 a = p[0], b = p[1];
    ushort8v v;
    v[0] = f2bf(a.x); v[1] = f2bf(a.y); v[2] = f2bf(a.z); v[3] = f2bf(a.w);
    v[4] = f2bf(b.x); v[5] = f2bf(b.y); v[6] = f2bf(b.z); v[7] = f2bf(b.w);
    *(ushort8v*)(out + (size_t)idx * 8) = v;
}

// ---------------------------------------------------------------------------
// Transpose-convert: out[c][r] = bf16(in[r][c]).  grid = (C/64, R/64), 256 thr
// ---------------------------------------------------------------------------
__global__ __launch_bounds__(256) void k_transpose_bf16(
    const float* __restrict__ in, u16* __restrict__ out, int R, int C)
{
    __shared__ u16 t[64][72];
    int r0 = blockIdx.y * 64, c0 = blockIdx.x * 64;
    int tid = threadIdx.x;
    for (int i = 0; i < 4; ++i) {
        int u = tid + i * 256;                 // 1024 float4 units
        int r = u >> 4, c4 = (u & 15) * 4;
        const float4 v = *(const float4*)(in + (size_t)(r0 + r) * C + c0 + c4);
        t[c4 + 0][r] = f2bf(v.x); t[c4 + 1][r] = f2bf(v.y);
        t[c4 + 2][r] = f2bf(v.z); t[c4 + 3][r] = f2bf(v.w);
    }
    __syncthreads();
    for (int i = 0; i < 4; ++i) {
        int u = tid + i * 256;                 // 1024 ushort4 units
        int c = u >> 4, r4 = (u & 15) * 4;
        ushort4v v;
        v[0] = t[c][r4]; v[1] = t[c][r4 + 1]; v[2] = t[c][r4 + 2]; v[3] = t[c][r4 + 3];
        *(ushort4v*)(out + (size_t)(c0 + c) * R + r0 + r4) = v;
    }
}

// ---------------------------------------------------------------------------
// MFMA bf16 GEMM, 128x128 tile, BK=32, 256 threads (4 waves, 2x2 of 64x64).
// global_load_lds width=16 staging, XOR swizzle on global-address side.
// MODE 0: output split-scattered to Q/K/V [B,H,S,D] bf16.
// MODE 1: output fp32 row-major [M][N].
// ---------------------------------------------------------------------------
template <int MODE>
__global__ __launch_bounds__(256) void k_gemm(
    const u16* __restrict__ A, const u16* __restrict__ Bt,
    u16* __restrict__ outQ, u16* __restrict__ outK, u16* __restrict__ outV,
    float* __restrict__ outF, int M, int N, int K)
{
    __shared__ u16 As[128][32];
    __shared__ u16 Bs[128][32];
    int tid = threadIdx.x;
    int lane = tid & 63, wid = tid >> 6;
    int wm = wid >> 1, wn = wid & 1;
    int lm = lane & 15, lq = lane >> 4;
    int row0 = blockIdx.y * 128, col0 = blockIdx.x * 128;

    int j  = lane >> 2;                              // 0..15
    int ck = (lane & 3) ^ (j & 3) ^ ((j >> 2) & 3);  // global 16B-chunk 0..3
    int rg0 = wid * 16;
    const u16* gA0 = A  + (size_t)(row0 + rg0      + j) * K + ck * 8;
    const u16* gA1 = A  + (size_t)(row0 + rg0 + 64 + j) * K + ck * 8;
    const u16* gB0 = Bt + (size_t)(col0 + rg0      + j) * K + ck * 8;
    const u16* gB1 = Bt + (size_t)(col0 + rg0 + 64 + j) * K + ck * 8;
    u16* lA0 = &As[rg0][0];      u16* lA1 = &As[rg0 + 64][0];
    u16* lB0 = &Bs[rg0][0];      u16* lB1 = &Bs[rg0 + 64][0];

    int colrd = ((lq ^ (lm & 3) ^ ((lm >> 2) & 3)) << 3);

    f32x4 acc[4][4];
    for (int a = 0; a < 4; ++a)
        for (int b = 0; b < 4; ++b) acc[a][b] = (f32x4){0.f, 0.f, 0.f, 0.f};

    for (int k0 = 0; k0 < K; k0 += 32) {
        gl_lds16(gA0 + k0, lA0);
        gl_lds16(gA1 + k0, lA1);
        gl_lds16(gB0 + k0, lB0);
        gl_lds16(gB1 + k0, lB1);
        __syncthreads();
        short8 af[4], bfr[4];
        for (int t = 0; t < 4; ++t) af[t]  = *(const short8*)&As[wm * 64 + t * 16 + lm][colrd];
        for (int t = 0; t < 4; ++t) bfr[t] = *(const short8*)&Bs[wn * 64 + t * 16 + lm][colrd];
        for (int it = 0; it < 4; ++it)
            for (int jt = 0; jt < 4; ++jt)
                acc[it][jt] = __builtin_amdgcn_mfma_f32_16x16x32_bf16(
                    af[it], bfr[jt], acc[it][jt], 0, 0, 0);
        __syncthreads();
    }

    if (MODE == 0) {
        int k3 = col0 >> 11;                   // uniform per block (128 | 2048)
        u16* dst = (k3 == 0) ? outQ : (k3 == 1) ? outK : outV;
        for (int it = 0; it < 4; ++it)
            for (int jt = 0; jt < 4; ++jt) {
                int c = col0 + wn * 64 + jt * 16 + lm;
                int hd = c & 2047, h = hd >> 7, d = hd & 127;
                for (int i = 0; i < 4; ++i) {
                    int r = row0 + wm * 64 + it * 16 + lq * 4 + i;
                    int b = r >> 11, s = r & 2047;
                    dst[((size_t)(b * 16 + h) * 2048 + s) * 128 + d] = f2bf(acc[it][jt][i]);
                }
            }
    } else {
        for (int it = 0; it < 4; ++it)
            for (int jt = 0; jt < 4; ++jt) {
                int c = col0 + wn * 64 + jt * 16 + lm;
                for (int i = 0; i < 4; ++i) {
                    int r = row0 + wm * 64 + it * 16 + lq * 4 + i;
                    outF[(size_t)r * N + c] = acc[it][jt][i];
                }
            }
    }
}

// ---------------------------------------------------------------------------
// RMSNorm + RoPE, in-place on [B,H,S,D] bf16 rows, then *oscale.
// For Q, oscale = 1/sqrt(D) * log2(e)  (base-2 softmax pre-scaling).
// ---------------------------------------------------------------------------
__global__ __launch_bounds__(256) void k_normrope(
    u16* __restrict__ X, const float* __restrict__ w, float oscale)
{
    int row = blockIdx.x * 4 + (threadIdx.x >> 6);
    int t = threadIdx.x & 63;
    int s = row & 2047;                        // S = 2048
    u16* p = X + (size_t)row * 128;
    float x0 = bf2f(p[t]), x1 = bf2f(p[t + 64]);
    float ss = x0 * x0 + x1 * x1;
    for (int m = 1; m < 64; m <<= 1) ss += __shfl_xor(ss, m);
    float r = rsqrtf(ss * (1.0f / 128.0f) + 0.01f);
    float a = x0 * r * w[t];
    float b = x1 * r * w[t + 64];
    float freq = exp2f(-13.287712379549449f * ((float)t * (1.0f / 64.0f)));
    float ang = (float)s * freq;
    float sn, c;
    sincosf(ang, &sn, &c);
    p[t]      = f2bf((a * c - b * sn) * oscale);
    p[t + 64] = f2bf((b * c + a * sn) * oscale);
}

// ---------------------------------------------------------------------------
// V transpose per head: [B,H,S,D] -> [B,H,D,S]. grid = (S/64, B*H)
// ---------------------------------------------------------------------------
__global__ __launch_bounds__(256) void k_vtrans(
    const u16* __restrict__ Vh, u16* __restrict__ Vt, int S)
{
    __shared__ u16 t[128][68];
    int bh = blockIdx.y, s0 = blockIdx.x * 64;
    int tid = threadIdx.x;
    const u16* src = Vh + ((size_t)bh * S + s0) * 128;
    for (int i = 0; i < 4; ++i) {
        int u = tid + i * 256;
        int r = u >> 4, c8 = (u & 15) * 8;
        ushort8v v = *(const ushort8v*)(src + (size_t)r * 128 + c8);
        for (int j = 0; j < 8; ++j) t[c8 + j][r] = v[j];
    }
    __syncthreads();
    u16* dst = Vt + (size_t)bh * 128 * S + s0;
    for (int i = 0; i < 8; ++i) {
        int u = tid + i * 256;
        int d = u >> 4, s4 = (u & 15) * 4;
        ushort4v v;
        v[0] = t[d][s4]; v[1] = t[d][s4 + 1]; v[2] = t[d][s4 + 2]; v[3] = t[d][s4 + 3];
        *(ushort4v*)(dst + (size_t)d * S + s4) = v;
    }
}

// ---------------------------------------------------------------------------
// Barrier-free causal flash attention. grid = (32, B*H), LPT order.
// K/V fragments streamed straight from global (L1/L2 serve the reuse);
// NO __syncthreads anywhere; LDS = per-wave sP only (8 KB/block).
// Q pre-scaled by 1/sqrt(D)*log2e, softmax in base-2 (exp2f = v_exp_f32).
// Causal mask hoisted: unmasked main loop + one masked diagonal step.
// ---------------------------------------------------------------------------
template <bool DIAG>
DEV void flash_step(int kb, int lq, int lm, int qcol, int S,
                    const u16* __restrict__ krow, const u16* __restrict__ vrow,
                    const short8 qf[4], f32x4 oacc[8],
                    float& mprev, float& lsum, u16* __restrict__ sPw)
{
    const u16* kk = krow + (size_t)kb * (64 * 128);
    f32x4 sacc[4];
    for (int nt = 0; nt < 4; ++nt) sacc[nt] = (f32x4){0.f, 0.f, 0.f, 0.f};
    for (int nt = 0; nt < 4; ++nt)
        for (int kc = 0; kc < 4; ++kc) {
            short8 kf = *(const short8*)(kk + nt * (16 * 128) + kc * 32);
            sacc[nt] = __builtin_amdgcn_mfma_f32_16x16x32_bf16(kf, qf[kc], sacc[nt], 0, 0, 0);
        }
    if (DIAG) {
        for (int nt = 0; nt < 4; ++nt)
            for (int i = 0; i < 4; ++i) {
                int kv = kb * 64 + nt * 16 + lq * 4 + i;
                if (kv > qcol) sacc[nt][i] = -1e30f;
            }
    }
    // row stats: 16 in-lane + 2 shfls (row lives on lanes lm, lm+16, ...)
    float mx = sacc[0][0];
    for (int nt = 0; nt < 4; ++nt)
        for (int i = 0; i < 4; ++i) mx = fmaxf(mx, sacc[nt][i]);
    mx = fmaxf(mx, __shfl_xor(mx, 16));
    mx = fmaxf(mx, __shfl_xor(mx, 32));
    float mnew = fmaxf(mprev, mx);
    float alpha = exp2f(mprev - mnew);
    float rs = 0.0f;
    for (int nt = 0; nt < 4; ++nt)
        for (int i = 0; i < 4; ++i) {
            float pv = exp2f(sacc[nt][i] - mnew);   // scores already *log2e
            sacc[nt][i] = pv;
            rs += pv;
        }
    rs += __shfl_xor(rs, 16);
    rs += __shfl_xor(rs, 32);
    lsum = lsum * alpha + rs;
    mprev = mnew;

    // P -> per-wave LDS (truncating v_perm pack; P in [0,1])
    for (int nt = 0; nt < 4; ++nt) {
        uint2 pk;
        pk.x = pk_bf_trunc(sacc[nt][0], sacc[nt][1]);
        pk.y = pk_bf_trunc(sacc[nt][2], sacc[nt][3]);
        *(uint2*)(sPw + (size_t)lm * 64 +
                  ((((nt << 1) + (lq >> 1)) ^ (lm & 7)) << 3) + ((lq & 1) << 2)) = pk;
    }

    float alphar[4];
    for (int i = 0; i < 4; ++i) alphar[i] = __shfl(alpha, lq * 4 + i, 16);
    for (int f = 0; f < 8; ++f)
        for (int i = 0; i < 4; ++i) oacc[f][i] *= alphar[i];

    short8 pf[2];
    for (int kc = 0; kc < 2; ++kc)
        pf[kc] = *(const short8*)(sPw + (size_t)lm * 64 + (((kc * 4 + lq) ^ (lm & 7)) << 3));
    const u16* vv = vrow + (size_t)kb * 64;
    for (int f = 0; f < 8; ++f)
        for (int kc = 0; kc < 2; ++kc) {
            short8 vf = *(const short8*)(vv + (size_t)(f * 16) * S + kc * 32);
            oacc[f] = __builtin_amdgcn_mfma_f32_16x16x32_bf16(pf[kc], vf, oacc[f], 0, 0, 0);
        }
}

__global__ __launch_bounds__(256, 4) void k_flash(
    const u16* __restrict__ Qh, const u16* __restrict__ Kh,
    const u16* __restrict__ Vt, u16* __restrict__ ctx, int S)
{
    __shared__ u16 sP[4][16][64];               // 8 KB, per-wave regions
    int qi = 31 - (int)blockIdx.x;              // LPT: big blocks first
    int bh = blockIdx.y;
    int b = bh >> 4, h = bh & 15;
    int tid = threadIdx.x, lane = tid & 63, w = tid >> 6;
    int lm = lane & 15, lq = lane >> 4;
    const u16* qbase = Qh + (size_t)bh * S * 128;
    const u16* krow  = Kh + (size_t)bh * S * 128 + (size_t)lm * 128 + lq * 8;
    const u16* vrow  = Vt + (size_t)bh * 128 * S + (size_t)lm * S + lq * 8;
    u16* sPw = &sP[w][0][0];

    int q0 = qi * 64 + w * 16;
    short8 qf[4];
    for (int kc = 0; kc < 4; ++kc)
        qf[kc] = *(const short8*)(qbase + (size_t)(q0 + lm) * 128 + kc * 32 + lq * 8);

    f32x4 oacc[8];
    for (int f = 0; f < 8; ++f) oacc[f] = (f32x4){0.f, 0.f, 0.f, 0.f};
    float mprev = -1e30f, lsum = 0.0f;
    int qcol = q0 + lm;

    for (int kb = 0; kb < qi; ++kb)
        flash_step<false>(kb, lq, lm, qcol, S, krow, vrow, qf, oacc, mprev, lsum, sPw);
    flash_step<true>(qi, lq, lm, qcol, S, krow, vrow, qf, oacc, mprev, lsum, sPw);

    float linv[4];
    for (int i = 0; i < 4; ++i)
        linv[i] = 1.0f / __shfl(lsum, lq * 4 + i, 16);
    u16* obase = ctx + (size_t)b * S * 2048 + h * 128;
    for (int f = 0; f < 8; ++f) {
        int d = f * 16 + lm;
        for (int i = 0; i < 4; ++i) {
            int s = qi * 64 + w * 16 + lq * 4 + i;
            obase[(size_t)s * 2048 + d] = f2bf(oacc[f][i] * linv[i]);
        }
    }
}

// ---------------------------------------------------------------------------
extern "C" void kernel_launch(void* const* d_in, const int* in_sizes, int n_in,
                              void* d_out, int out_size, void* d_ws, size_t ws_size,
                              hipStream_t stream)
{
    const float* x        = (const float*)d_in[0];
    const float* w_qkv    = (const float*)d_in[1];
    const float* w_proj   = (const float*)d_in[2];
    const float* q_norm_w = (const float*)d_in[3];
    const float* k_norm_w = (const float*)d_in[4];
    float* out = (float*)d_out;

    const int B = 4, S = 2048, E = 2048, H = 16;
    const int M  = B * S;        // 8192
    const int N1 = 3 * E;        // 6144
    const int N2 = E;            // 2048
    // 1/sqrt(128) * log2(e)
    const float QSCALE = 0.12751743f;

    char* ws = (char*)d_ws;
    size_t off = 0;
    auto alloc = [&](size_t bytes) {
        char* p = ws + off;
        off += (bytes + 255) & ~(size_t)255;
        return p;
    };
    u16* Wpt  = (u16*)alloc((size_t)E * E * 2);        // live to end
    char* regR = alloc((size_t)M * N1 * 2);
    u16* Wqt  = (u16*)regR;                            //   dead after GEMM1
    u16* ctxp = (u16*)regR;                            //   written by flash
    u16* Qh = (u16*)alloc((size_t)M * E * 2);
    u16* Kh = (u16*)alloc((size_t)M * E * 2);
    u16* Vh = (u16*)alloc((size_t)M * E * 2);
    char* regV = alloc((size_t)M * E * 2);
    u16* xb = (u16*)regV;                              //   dead after GEMM1
    u16* Vt = (u16*)regV;                              //   written by vtrans

    // 0. x -> bf16
    k_x2bf<<<(M * E) / (256 * 8), 256, 0, stream>>>(x, xb);
    // 1. weight transpose/convert
    k_transpose_bf16<<<dim3(N1 / 64, E / 64), 256, 0, stream>>>(w_qkv, Wqt, E, N1);
    k_transpose_bf16<<<dim3(N2 / 64, E / 64), 256, 0, stream>>>(w_proj, Wpt, E, N2);
    // 2. fused QKV projection, scatter to [B,H,S,D]
    k_gemm<0><<<dim3(N1 / 128, M / 128), 256, 0, stream>>>(
        xb, Wqt, Qh, Kh, Vh, nullptr, M, N1, E);
    // 3. RMSNorm + RoPE (Q additionally pre-scaled for base-2 softmax)
    k_normrope<<<(B * H * S) / 4, 256, 0, stream>>>(Qh, q_norm_w, QSCALE);
    k_normrope<<<(B * H * S) / 4, 256, 0, stream>>>(Kh, k_norm_w, 1.0f);
    // 4. transpose V per head (overwrites xb region — xb dead by now)
    k_vtrans<<<dim3(S / 64, B * H), 256, 0, stream>>>(Vh, Vt, S);
    // 5. barrier-free causal flash attention -> ctx [B,S,H*D]
    k_flash<<<dim3(32, B * H), 256, 0, stream>>>(Qh, Kh, Vt, ctxp, S);
    // 6. output projection -> fp32 out
    k_gemm<1><<<dim3(N2 / 128, M / 128), 256, 0, stream>>>(
        ctxp, Wpt, nullptr, nullptr, nullptr, out, M, N2, E);
}

// Round 5
// 761.212 us; speedup vs baseline: 1.9239x; 1.9239x over previous
//
#include <hip/hip_runtime.h>
#include <hip/hip_bf16.h>
#include <math.h>

typedef unsigned short u16;
typedef __attribute__((ext_vector_type(8))) short short8;     // 8 bf16 (4 VGPRs)
typedef __attribute__((ext_vector_type(4))) float f32x4;
typedef __attribute__((ext_vector_type(4))) unsigned short ushort4v;
typedef __attribute__((ext_vector_type(8))) unsigned short ushort8v;

#define DEV static __device__ __forceinline__

DEV u16 f2bf(float f) {
    unsigned int x = __builtin_bit_cast(unsigned int, f);
    x += 0x7fffu + ((x >> 16) & 1u);      // round-to-nearest-even
    return (u16)(x >> 16);
}
DEV float bf2f(u16 u) {
    unsigned int x = ((unsigned int)u) << 16;
    return __builtin_bit_cast(float, x);
}
// pack two f32 -> two bf16 (truncating) in one v_perm_b32
DEV unsigned int pk_bf_trunc(float lo, float hi) {
    return __builtin_amdgcn_perm(__builtin_bit_cast(unsigned int, hi),
                                 __builtin_bit_cast(unsigned int, lo), 0x07060302u);
}

// async global->LDS, 16B per lane; LDS dest = wave-uniform base + lane*16
DEV void gl_lds16(const u16* g, u16* l) {
    __builtin_amdgcn_global_load_lds(
        (const __attribute__((address_space(1))) void*)g,
        (__attribute__((address_space(3))) void*)l, 16, 0, 0);
}

// ---------------------------------------------------------------------------
// x fp32 -> bf16, 1 unit = 8 elems. grid = n/(256*8)
// ---------------------------------------------------------------------------
__global__ __launch_bounds__(256) void k_x2bf(
    const float* __restrict__ in, u16* __restrict__ out)
{
    int idx = blockIdx.x * 256 + threadIdx.x;
    const float4* p = (const float4*)in + (size_t)idx * 2;
    float4 a = p[0], b = p[1];
    ushort8v v;
    v[0] = f2bf(a.x); v[1] = f2bf(a.y); v[2] = f2bf(a.z); v[3] = f2bf(a.w);
    v[4] = f2bf(b.x); v[5] = f2bf(b.y); v[6] = f2bf(b.z); v[7] = f2bf(b.w);
    *(ushort8v*)(out + (size_t)idx * 8) = v;
}

// ---------------------------------------------------------------------------
// Transpose-convert: out[c][r] = bf16(in[r][c]).  grid = (C/64, R/64), 256 thr
// ---------------------------------------------------------------------------
__global__ __launch_bounds__(256) void k_transpose_bf16(
    const float* __restrict__ in, u16* __restrict__ out, int R, int C)
{
    __shared__ u16 t[64][72];
    int r0 = blockIdx.y * 64, c0 = blockIdx.x * 64;
    int tid = threadIdx.x;
    for (int i = 0; i < 4; ++i) {
        int u = tid + i * 256;                 // 1024 float4 units
        int r = u >> 4, c4 = (u & 15) * 4;
        const float4 v = *(const float4*)(in + (size_t)(r0 + r) * C + c0 + c4);
        t[c4 + 0][r] = f2bf(v.x); t[c4 + 1][r] = f2bf(v.y);
        t[c4 + 2][r] = f2bf(v.z); t[c4 + 3][r] = f2bf(v.w);
    }
    __syncthreads();
    for (int i = 0; i < 4; ++i) {
        int u = tid + i * 256;                 // 1024 ushort4 units
        int c = u >> 4, r4 = (u & 15) * 4;
        ushort4v v;
        v[0] = t[c][r4]; v[1] = t[c][r4 + 1]; v[2] = t[c][r4 + 2]; v[3] = t[c][r4 + 3];
        *(ushort4v*)(out + (size_t)(c0 + c) * R + r0 + r4) = v;
    }
}

// ---------------------------------------------------------------------------
// MFMA bf16 GEMM, 128x128 tile, BK=32, 256 threads (4 waves, 2x2 of 64x64).
// global_load_lds width=16 staging, XOR swizzle on global-address side.
// MODE 0: output split-scattered to Q/K/V [B,H,S,D] bf16.
// MODE 1: output fp32 row-major [M][N].
// ---------------------------------------------------------------------------
template <int MODE>
__global__ __launch_bounds__(256) void k_gemm(
    const u16* __restrict__ A, const u16* __restrict__ Bt,
    u16* __restrict__ outQ, u16* __restrict__ outK, u16* __restrict__ outV,
    float* __restrict__ outF, int M, int N, int K)
{
    __shared__ u16 As[128][32];
    __shared__ u16 Bs[128][32];
    int tid = threadIdx.x;
    int lane = tid & 63, wid = tid >> 6;
    int wm = wid >> 1, wn = wid & 1;
    int lm = lane & 15, lq = lane >> 4;
    int row0 = blockIdx.y * 128, col0 = blockIdx.x * 128;

    int j  = lane >> 2;                              // 0..15
    int ck = (lane & 3) ^ (j & 3) ^ ((j >> 2) & 3);  // global 16B-chunk 0..3
    int rg0 = wid * 16;
    const u16* gA0 = A  + (size_t)(row0 + rg0      + j) * K + ck * 8;
    const u16* gA1 = A  + (size_t)(row0 + rg0 + 64 + j) * K + ck * 8;
    const u16* gB0 = Bt + (size_t)(col0 + rg0      + j) * K + ck * 8;
    const u16* gB1 = Bt + (size_t)(col0 + rg0 + 64 + j) * K + ck * 8;
    u16* lA0 = &As[rg0][0];      u16* lA1 = &As[rg0 + 64][0];
    u16* lB0 = &Bs[rg0][0];      u16* lB1 = &Bs[rg0 + 64][0];

    int colrd = ((lq ^ (lm & 3) ^ ((lm >> 2) & 3)) << 3);

    f32x4 acc[4][4];
    for (int a = 0; a < 4; ++a)
        for (int b = 0; b < 4; ++b) acc[a][b] = (f32x4){0.f, 0.f, 0.f, 0.f};

    for (int k0 = 0; k0 < K; k0 += 32) {
        gl_lds16(gA0 + k0, lA0);
        gl_lds16(gA1 + k0, lA1);
        gl_lds16(gB0 + k0, lB0);
        gl_lds16(gB1 + k0, lB1);
        __syncthreads();
        short8 af[4], bfr[4];
        for (int t = 0; t < 4; ++t) af[t]  = *(const short8*)&As[wm * 64 + t * 16 + lm][colrd];
        for (int t = 0; t < 4; ++t) bfr[t] = *(const short8*)&Bs[wn * 64 + t * 16 + lm][colrd];
        for (int it = 0; it < 4; ++it)
            for (int jt = 0; jt < 4; ++jt)
                acc[it][jt] = __builtin_amdgcn_mfma_f32_16x16x32_bf16(
                    af[it], bfr[jt], acc[it][jt], 0, 0, 0);
        __syncthreads();
    }

    if (MODE == 0) {
        int k3 = col0 >> 11;                   // uniform per block (128 | 2048)
        u16* dst = (k3 == 0) ? outQ : (k3 == 1) ? outK : outV;
        for (int it = 0; it < 4; ++it)
            for (int jt = 0; jt < 4; ++jt) {
                int c = col0 + wn * 64 + jt * 16 + lm;
                int hd = c & 2047, h = hd >> 7, d = hd & 127;
                for (int i = 0; i < 4; ++i) {
                    int r = row0 + wm * 64 + it * 16 + lq * 4 + i;
                    int b = r >> 11, s = r & 2047;
                    dst[((size_t)(b * 16 + h) * 2048 + s) * 128 + d] = f2bf(acc[it][jt][i]);
                }
            }
    } else {
        for (int it = 0; it < 4; ++it)
            for (int jt = 0; jt < 4; ++jt) {
                int c = col0 + wn * 64 + jt * 16 + lm;
                for (int i = 0; i < 4; ++i) {
                    int r = row0 + wm * 64 + it * 16 + lq * 4 + i;
                    outF[(size_t)r * N + c] = acc[it][jt][i];
                }
            }
    }
}

// ---------------------------------------------------------------------------
// RMSNorm + RoPE, in-place on [B,H,S,D] bf16 rows, then *oscale.
// For Q, oscale = 1/sqrt(D) * log2(e)  (base-2 softmax pre-scaling).
// ---------------------------------------------------------------------------
__global__ __launch_bounds__(256) void k_normrope(
    u16* __restrict__ X, const float* __restrict__ w, float oscale)
{
    int row = blockIdx.x * 4 + (threadIdx.x >> 6);
    int t = threadIdx.x & 63;
    int s = row & 2047;                        // S = 2048
    u16* p = X + (size_t)row * 128;
    float x0 = bf2f(p[t]), x1 = bf2f(p[t + 64]);
    float ss = x0 * x0 + x1 * x1;
    for (int m = 1; m < 64; m <<= 1) ss += __shfl_xor(ss, m);
    float r = rsqrtf(ss * (1.0f / 128.0f) + 0.01f);
    float a = x0 * r * w[t];
    float b = x1 * r * w[t + 64];
    float freq = exp2f(-13.287712379549449f * ((float)t * (1.0f / 64.0f)));
    float ang = (float)s * freq;
    float sn, c;
    sincosf(ang, &sn, &c);
    p[t]      = f2bf((a * c - b * sn) * oscale);
    p[t + 64] = f2bf((b * c + a * sn) * oscale);
}

// ---------------------------------------------------------------------------
// V transpose per head: [B,H,S,D] -> [B,H,D,S]. grid = (S/64, B*H)
// ---------------------------------------------------------------------------
__global__ __launch_bounds__(256) void k_vtrans(
    const u16* __restrict__ Vh, u16* __restrict__ Vt, int S)
{
    __shared__ u16 t[128][68];
    int bh = blockIdx.y, s0 = blockIdx.x * 64;
    int tid = threadIdx.x;
    const u16* src = Vh + ((size_t)bh * S + s0) * 128;
    for (int i = 0; i < 4; ++i) {
        int u = tid + i * 256;
        int r = u >> 4, c8 = (u & 15) * 8;
        ushort8v v = *(const ushort8v*)(src + (size_t)r * 128 + c8);
        for (int j = 0; j < 8; ++j) t[c8 + j][r] = v[j];
    }
    __syncthreads();
    u16* dst = Vt + (size_t)bh * 128 * S + s0;
    for (int i = 0; i < 8; ++i) {
        int u = tid + i * 256;
        int d = u >> 4, s4 = (u & 15) * 4;
        ushort4v v;
        v[0] = t[d][s4]; v[1] = t[d][s4 + 1]; v[2] = t[d][s4 + 2]; v[3] = t[d][s4 + 3];
        *(ushort4v*)(dst + (size_t)d * S + s4) = v;
    }
}

// ---------------------------------------------------------------------------
// Causal flash attention, LDS-staged with phase-offset single-buffer prefetch.
// grid = (32, B*H), LPT order. 4 waves x 16 q-rows, KV tiles of 64.
// K consumed early (QK), V consumed late (PV) -> issue K(kb+1) after the
// post-QK barrier (covered by softmax+PV), V(kb+1) after the post-PV barrier
// (covered by next QK). No load is drained right after issue. Staging via
// global_load_lds w=16, XOR swizzle on the global-address side.
// Q pre-scaled by 1/sqrt(D)*log2e -> base-2 softmax (bare v_exp_f32).
// Causal mask hoisted into a single diagonal step. LDS 40KB -> 4 blocks/CU.
// ---------------------------------------------------------------------------
template <bool DIAG>
DEV void flash_core(int kb, int lq, int lm, int qcol,
                    const u16* __restrict__ sKf, const u16* __restrict__ sVf,
                    const short8 qf[4], f32x4 oacc[8],
                    float& mprev, float& lsum, u16* __restrict__ sPw,
                    f32x4 sacc[4])
{
    for (int nt = 0; nt < 4; ++nt) sacc[nt] = (f32x4){0.f, 0.f, 0.f, 0.f};
    for (int nt = 0; nt < 4; ++nt)
        for (int kc = 0; kc < 4; ++kc) {
            short8 kf = *(const short8*)(sKf + (nt * 16 + lm) * 128 +
                                         (((kc * 4 + lq) ^ lm) << 3));
            sacc[nt] = __builtin_amdgcn_mfma_f32_16x16x32_bf16(kf, qf[kc], sacc[nt], 0, 0, 0);
        }
}

DEV void flash_softmax_pv(int lq, int lm, int S_dummy,
                          const u16* __restrict__ sVf,
                          f32x4 oacc[8], float& mprev, float& lsum,
                          u16* __restrict__ sPw, f32x4 sacc[4])
{
    float mx = sacc[0][0];
    for (int nt = 0; nt < 4; ++nt)
        for (int i = 0; i < 4; ++i) mx = fmaxf(mx, sacc[nt][i]);
    mx = fmaxf(mx, __shfl_xor(mx, 16));
    mx = fmaxf(mx, __shfl_xor(mx, 32));
    float mnew = fmaxf(mprev, mx);
    float alpha = exp2f(mprev - mnew);
    float rs = 0.0f;
    for (int nt = 0; nt < 4; ++nt)
        for (int i = 0; i < 4; ++i) {
            float pv = exp2f(sacc[nt][i] - mnew);   // scores pre-scaled by log2e
            sacc[nt][i] = pv;
            rs += pv;
        }
    rs += __shfl_xor(rs, 16);
    rs += __shfl_xor(rs, 32);
    lsum = lsum * alpha + rs;
    mprev = mnew;

    // P -> per-wave LDS (truncating v_perm pack; P in [0,1])
    for (int nt = 0; nt < 4; ++nt) {
        uint2 pk;
        pk.x = pk_bf_trunc(sacc[nt][0], sacc[nt][1]);
        pk.y = pk_bf_trunc(sacc[nt][2], sacc[nt][3]);
        *(uint2*)(sPw + lm * 64 +
                  ((((nt << 1) + (lq >> 1)) ^ (lm & 7)) << 3) + ((lq & 1) << 2)) = pk;
    }

    float alphar[4];
    for (int i = 0; i < 4; ++i) alphar[i] = __shfl(alpha, lq * 4 + i, 16);
    for (int f = 0; f < 8; ++f)
        for (int i = 0; i < 4; ++i) oacc[f][i] *= alphar[i];

    short8 pf[2];
    for (int kc = 0; kc < 2; ++kc)
        pf[kc] = *(const short8*)(sPw + lm * 64 + (((kc * 4 + lq) ^ (lm & 7)) << 3));
    for (int f = 0; f < 8; ++f)
        for (int kc = 0; kc < 2; ++kc) {
            short8 vf = *(const short8*)(sVf + (f * 16 + lm) * 64 +
                                         (((kc * 4 + lq) ^ (lm & 7)) << 3));
            oacc[f] = __builtin_amdgcn_mfma_f32_16x16x32_bf16(pf[kc], vf, oacc[f], 0, 0, 0);
        }
}

__global__ __launch_bounds__(256, 4) void k_flash(
    const u16* __restrict__ Qh, const u16* __restrict__ Kh,
    const u16* __restrict__ Vt, u16* __restrict__ ctx, int S)
{
    __shared__ u16 sK[64 * 128];                // 16 KB [kv][d], swizzled
    __shared__ u16 sV[128 * 64];                // 16 KB [d][kv], swizzled
    __shared__ u16 sP[4 * 16 * 64];             //  8 KB per-wave regions
    int qi = 31 - (int)blockIdx.x;              // LPT: big blocks first
    int bh = blockIdx.y;
    int b = bh >> 4, h = bh & 15;
    int tid = threadIdx.x, lane = tid & 63, w = tid >> 6;
    int lm = lane & 15, lq = lane >> 4;
    const u16* qbase = Qh + (size_t)bh * S * 128;
    u16* sPw = &sP[w * 16 * 64];

    // --- staging source pointers (global-side XOR swizzle) ---
    // K: per instr i, rows r0=i*16+w*4 .. +3; lane (lq,lm) -> row r0+lq,
    //    global chunk lm ^ ((w*4+lq)&15)  (i*16 doesn't affect &15)
    int kck = lm ^ (w * 4 + lq);
    const u16* kg = Kh + (size_t)bh * S * 128 + (size_t)(w * 4 + lq) * 128 + kck * 8;
    // V: per instr i, rows d0=i*32+w*8 .. +7; lane (hi3=lane>>3, c3=lane&7)
    //    -> row d0+hi3, global chunk c3 ^ (hi3&7)
    int hi3 = lane >> 3, c3 = lane & 7;
    int vck = c3 ^ (hi3 & 7);
    const u16* vg = Vt + (size_t)bh * 128 * S + (size_t)(w * 8 + hi3) * S + vck * 8;

    auto stageK = [&](int kb) {
        const u16* g = kg + (size_t)kb * (64 * 128);
        for (int i = 0; i < 4; ++i)
            gl_lds16(g + i * (16 * 128), sK + (i * 16 + w * 4) * 128);
    };
    auto stageV = [&](int kb) {
        const u16* g = vg + kb * 64;
        for (int i = 0; i < 4; ++i)
            gl_lds16(g + (size_t)(i * 32) * S, sV + (i * 32 + w * 8) * 64);
    };

    int q0 = qi * 64 + w * 16;
    short8 qf[4];
    for (int kc = 0; kc < 4; ++kc)
        qf[kc] = *(const short8*)(qbase + (size_t)(q0 + lm) * 128 + kc * 32 + lq * 8);

    f32x4 oacc[8];
    for (int f = 0; f < 8; ++f) oacc[f] = (f32x4){0.f, 0.f, 0.f, 0.f};
    float mprev = -1e30f, lsum = 0.0f;
    int qcol = q0 + lm;

    stageK(0);
    stageV(0);
    __syncthreads();

    f32x4 sacc[4];
    for (int kb = 0; kb < qi; ++kb) {
        flash_core<false>(kb, lq, lm, qcol, sK, sV, qf, oacc, mprev, lsum, sPw, sacc);
        __syncthreads();                       // A: sK free; drains V(kb) loads
        stageK(kb + 1);                        // covered by softmax+PV
        flash_softmax_pv(lq, lm, S, sV, oacc, mprev, lsum, sPw, sacc);
        __syncthreads();                       // B: sV free; drains K(kb+1) loads
        stageV(kb + 1);                        // covered by next QK
    }
    // diagonal step (masked); sK/sV valid for kb=qi after last barrier
    flash_core<true>(qi, lq, lm, qcol, sK, sV, qf, oacc, mprev, lsum, sPw, sacc);
    for (int nt = 0; nt < 4; ++nt)
        for (int i = 0; i < 4; ++i) {
            int kv = qi * 64 + nt * 16 + lq * 4 + i;
            if (kv > qcol) sacc[nt][i] = -1e30f;
        }
    __syncthreads();                           // drains V(qi) loads
    flash_softmax_pv(lq, lm, S, sV, oacc, mprev, lsum, sPw, sacc);

    float linv[4];
    for (int i = 0; i < 4; ++i)
        linv[i] = 1.0f / __shfl(lsum, lq * 4 + i, 16);
    u16* obase = ctx + (size_t)b * S * 2048 + h * 128;
    for (int f = 0; f < 8; ++f) {
        int d = f * 16 + lm;
        for (int i = 0; i < 4; ++i) {
            int s = qi * 64 + w * 16 + lq * 4 + i;
            obase[(size_t)s * 2048 + d] = f2bf(oacc[f][i] * linv[i]);
        }
    }
}

// ---------------------------------------------------------------------------
extern "C" void kernel_launch(void* const* d_in, const int* in_sizes, int n_in,
                              void* d_out, int out_size, void* d_ws, size_t ws_size,
                              hipStream_t stream)
{
    const float* x        = (const float*)d_in[0];
    const float* w_qkv    = (const float*)d_in[1];
    const float* w_proj   = (const float*)d_in[2];
    const float* q_norm_w = (const float*)d_in[3];
    const float* k_norm_w = (const float*)d_in[4];
    float* out = (float*)d_out;

    const int B = 4, S = 2048, E = 2048, H = 16;
    const int M  = B * S;        // 8192
    const int N1 = 3 * E;        // 6144
    const int N2 = E;            // 2048
    // 1/sqrt(128) * log2(e)
    const float QSCALE = 0.12751743f;

    char* ws = (char*)d_ws;
    size_t off = 0;
    auto alloc = [&](size_t bytes) {
        char* p = ws + off;
        off += (bytes + 255) & ~(size_t)255;
        return p;
    };
    u16* Wpt  = (u16*)alloc((size_t)E * E * 2);        // live to end
    char* regR = alloc((size_t)M * N1 * 2);
    u16* Wqt  = (u16*)regR;                            //   dead after GEMM1
    u16* ctxp = (u16*)regR;                            //   written by flash
    u16* Qh = (u16*)alloc((size_t)M * E * 2);
    u16* Kh = (u16*)alloc((size_t)M * E * 2);
    u16* Vh = (u16*)alloc((size_t)M * E * 2);
    char* regV = alloc((size_t)M * E * 2);
    u16* xb = (u16*)regV;                              //   dead after GEMM1
    u16* Vt = (u16*)regV;                              //   written by vtrans

    // 0. x -> bf16
    k_x2bf<<<(M * E) / (256 * 8), 256, 0, stream>>>(x, xb);
    // 1. weight transpose/convert
    k_transpose_bf16<<<dim3(N1 / 64, E / 64), 256, 0, stream>>>(w_qkv, Wqt, E, N1);
    k_transpose_bf16<<<dim3(N2 / 64, E / 64), 256, 0, stream>>>(w_proj, Wpt, E, N2);
    // 2. fused QKV projection, scatter to [B,H,S,D]
    k_gemm<0><<<dim3(N1 / 128, M / 128), 256, 0, stream>>>(
        xb, Wqt, Qh, Kh, Vh, nullptr, M, N1, E);
    // 3. RMSNorm + RoPE (Q additionally pre-scaled for base-2 softmax)
    k_normrope<<<(B * H * S) / 4, 256, 0, stream>>>(Qh, q_norm_w, QSCALE);
    k_normrope<<<(B * H * S) / 4, 256, 0, stream>>>(Kh, k_norm_w, 1.0f);
    // 4. transpose V per head (overwrites xb region — xb dead by now)
    k_vtrans<<<dim3(S / 64, B * H), 256, 0, stream>>>(Vh, Vt, S);
    // 5. causal flash attention -> ctx [B,S,H*D]
    k_flash<<<dim3(32, B * H), 256, 0, stream>>>(Qh, Kh, Vt, ctxp, S);
    // 6. output projection -> fp32 out
    k_gemm<1><<<dim3(N2 / 128, M / 128), 256, 0, stream>>>(
        ctxp, Wpt, nullptr, nullptr, nullptr, out, M, N2, E);
}